// Round 7
// baseline (14.684 us; speedup 1.0000x reference)
//
#include <hip/hip_runtime.h>
#include <cfloat>

// DiffGSTileSampler, fused single kernel, 512 threads/block.
// Per 16x16 tile: cull 1024 gaussians from global (means float2 + a,c) while
// staging gather-fields (covs/depth/colors) to LDS -> ballot-compact: hit
// lanes gather b/depth/rgb, invert cov in registers, write depth to slot ->
// hit lanes self-rank by (depth, slot) and write sorted inverted records to
// g2 -> front-to-back composite split across thread halves (exact by
// compositing associativity). Culling exact: contribution needs q<=11.09<11.3.

constexpr int P_GAUSS = 1024;
constexpr int IMG_H = 256;
constexpr int IMG_W = 256;
constexpr float Q_GATE = 11.2f;   // alpha>=1/255 iff q<=2*ln255=11.0898
constexpr float Q_CULL = 11.3f;

// staged-raw layout (float offsets): covs | depth | colors
constexpr int RAW_COVS  = 0;      // 3072 floats
constexpr int RAW_DEPTH = 3072;   // 1024
constexpr int RAW_COLS  = 4096;   // 3072
constexpr int RAW_TOT   = 7168;   // 28 KB

__global__ __launch_bounds__(512) void gs_fused(
    const float* __restrict__ means,   // P*2
    const float* __restrict__ covs,    // P*3
    const float* __restrict__ depth,   // P
    const float* __restrict__ colors,  // P*3
    float* __restrict__ out)           // 3*H*W chw
{
    __shared__ float rawbuf[RAW_TOT];       // gather fields; reused for partial composite
    __shared__ float g2[P_GAUSS * 8];       // sorted inverted records
    __shared__ float sdepth[P_GAUSS + 4];   // survivor depths (+pad)
    __shared__ int   cnt16[16];

    const int tid = threadIdx.x;
    const int wid = tid >> 6;
    const int lane = tid & 63;

    const float tx0 = (float)(blockIdx.x * 16) + 0.5f;
    const float tx1 = tx0 + 15.0f;
    const float ty0 = (float)(blockIdx.y * 16) + 0.5f;
    const float ty1 = ty0 + 15.0f;

    // ---- staging of gather fields (concurrent with cull loads) ----
    {
        float4* rv = reinterpret_cast<float4*>(rawbuf);
        const float4* cv = reinterpret_cast<const float4*>(covs);
        const float4* dv = reinterpret_cast<const float4*>(depth);
        const float4* lv = reinterpret_cast<const float4*>(colors);
        rv[RAW_COVS / 4 + tid] = cv[tid];
        rv[RAW_COLS / 4 + tid] = lv[tid];
        if (tid < 256) {
            rv[RAW_COVS / 4 + 512 + tid] = cv[512 + tid];
            rv[RAW_COLS / 4 + 512 + tid] = lv[512 + tid];
            rv[RAW_DEPTH / 4 + tid]      = dv[tid];
        }
    }

    // ---- cull directly from global; ballot counts ----
    float mx[2], my[2], ca[2], cc[2];
    unsigned long long msk[2];
    bool hit[2];
#pragma unroll
    for (int r = 0; r < 2; ++r) {
        const int p = r * 512 + tid;
        const float2 m2 = reinterpret_cast<const float2*>(means)[p];
        mx[r] = m2.x; my[r] = m2.y;
        ca[r] = covs[3 * p + 0];
        cc[r] = covs[3 * p + 2];
        const float rx = sqrtf(Q_CULL * ca[r]);
        const float ry = sqrtf(Q_CULL * cc[r]);
        hit[r] = (mx[r] + rx >= tx0) && (mx[r] - rx <= tx1) &&
                 (my[r] + ry >= ty0) && (my[r] - ry <= ty1);
        msk[r] = __ballot(hit[r]);
        if (lane == 0) cnt16[r * 8 + wid] = __popcll(msk[r]);
    }
    __syncthreads();   // cnt16 visible; staging ds_writes complete

    int c16[16];
#pragma unroll
    for (int k = 0; k < 16; ++k) c16[k] = cnt16[k];
    int total = 0;
#pragma unroll
    for (int k = 0; k < 16; ++k) total += c16[k];

    // ---- scatter: hit lanes gather fields, invert cov in regs, write depth ----
    float4 rec0[2], rec1[2];
    float dpr[2];
    int slot[2];
#pragma unroll
    for (int r = 0; r < 2; ++r) {
        if (hit[r]) {
            const int p = r * 512 + tid;
            const float cb  = rawbuf[RAW_COVS + 3 * p + 1];
            const float dp  = rawbuf[RAW_DEPTH + p];
            const float cr  = rawbuf[RAW_COLS + 3 * p + 0];
            const float cg  = rawbuf[RAW_COLS + 3 * p + 1];
            const float cbl = rawbuf[RAW_COLS + 3 * p + 2];
            const int key = r * 8 + wid;
            int base = 0;
            for (int k = 0; k < key; ++k) base += c16[k];
            const int s = base + __popcll(msk[r] & ((1ull << lane) - 1ull));
            const float inv = 1.0f / (ca[r] * cc[r] - cb * cb);
            rec0[r] = make_float4(mx[r], my[r], cc[r] * inv, -cb * inv);  // mx,my,ia,ib
            rec1[r] = make_float4(ca[r] * inv, cr, cg, cbl);              // ic,r,g,b
            dpr[r] = dp;
            slot[r] = s;
            sdepth[s] = dp;
        }
    }
    if (tid < 4) sdepth[total + tid] = FLT_MAX;   // pad for float4 rank loop
    __syncthreads();

    // ---- hit lanes self-rank by (depth, slot); write sorted records to g2 ----
    const int limit4 = (total + 3) >> 2;
#pragma unroll
    for (int r = 0; r < 2; ++r) {
        if (hit[r]) {
            const float d = dpr[r];
            const int s = slot[r];
            int rank = 0;
            const float4* sd4 = reinterpret_cast<const float4*>(sdepth);
            for (int jj = 0; jj < limit4; ++jj) {
                const float4 d4 = sd4[jj];
                const int j = 4 * jj;
                rank += (d4.x < d || (d4.x == d && j + 0 < s)) ? 1 : 0;
                rank += (d4.y < d || (d4.y == d && j + 1 < s)) ? 1 : 0;
                rank += (d4.z < d || (d4.z == d && j + 2 < s)) ? 1 : 0;
                rank += (d4.w < d || (d4.w == d && j + 3 < s)) ? 1 : 0;
            }
            float4* dst = reinterpret_cast<float4*>(g2 + rank * 8);
            dst[0] = rec0[r];
            dst[1] = rec1[r];
        }
    }
    __syncthreads();

    // ---- composite: split list halves across thread halves ----
    const int h = (total + 1) >> 1;
    float4* part = reinterpret_cast<float4*>(rawbuf);   // rawbuf dead -> reuse
    const float4* gv = reinterpret_cast<const float4*>(g2);

    const int pixid = tid & 255;
    const float px = tx0 + (float)(pixid & 15);
    const float py = ty0 + (float)(pixid >> 4);
    const int lo = (tid < 256) ? 0 : h;
    const int hi = (tid < 256) ? h : total;

    float T = 1.0f;
    float acr = 0.0f, acg = 0.0f, acb = 0.0f;

    float4 A0, B0, A1, B1;
    if (lo + 0 < hi) { A0 = gv[2 * lo + 0]; B0 = gv[2 * lo + 1]; }
    if (lo + 1 < hi) { A1 = gv[2 * lo + 2]; B1 = gv[2 * lo + 3]; }
    for (int p = lo; p < hi; ++p) {
        const float4 c0 = A0;   // mx, my, ia, ib
        const float4 c1 = B0;   // ic, r, g, b
        A0 = A1; B0 = B1;
        if (p + 2 < hi) { A1 = gv[2 * p + 4]; B1 = gv[2 * p + 5]; }
        const float dx = px - c0.x;
        const float dy = py - c0.y;
        const float q = c0.z * dx * dx + 2.0f * c0.w * (dx * dy) + c1.x * dy * dy;
        float alpha = fminf(0.99f, __expf(-0.5f * q));
        alpha = (q < Q_GATE && alpha >= (1.0f / 255.0f)) ? alpha : 0.0f;
        const float w = alpha * T;
        acr += w * c1.y;
        acg += w * c1.z;
        acb += w * c1.w;
        T *= (1.0f - alpha);
    }
    if (tid >= 256) part[pixid] = make_float4(acr, acg, acb, T);
    __syncthreads();

    if (tid < 256) {
        const float4 pb = part[pixid];
        acr += T * pb.x;          // exact alpha-compositing associativity
        acg += T * pb.y;
        acb += T * pb.z;
        const int pix = (blockIdx.y * 16 + (pixid >> 4)) * IMG_W + (blockIdx.x * 16 + (pixid & 15));
        out[0 * IMG_H * IMG_W + pix] = acr;
        out[1 * IMG_H * IMG_W + pix] = acg;
        out[2 * IMG_H * IMG_W + pix] = acb;
    }
}

extern "C" void kernel_launch(void* const* d_in, const int* in_sizes, int n_in,
                              void* d_out, int out_size, void* d_ws, size_t ws_size,
                              hipStream_t stream) {
    const float* means  = (const float*)d_in[0];
    const float* covs   = (const float*)d_in[1];
    const float* depth  = (const float*)d_in[2];
    const float* colors = (const float*)d_in[3];
    float* out = (float*)d_out;

    gs_fused<<<dim3(IMG_W / 16, IMG_H / 16), dim3(512), 0, stream>>>(
        means, covs, depth, colors, out);
}

// Round 8
// 13.778 us; speedup vs baseline: 1.0658x; 1.0658x over previous
//
#include <hip/hip_runtime.h>
#include <cfloat>

// DiffGSTileSampler, fused single kernel, 512 threads/block.  (round-6 best)
// Per 16x16 tile: cull 1024 gaussians straight from global (means float2 +
// a,c scalars; all L2-resident) while staging covs/depth/colors to LDS ->
// ballot-compact survivors (original order) -> rank-sort by (depth, orig idx)
// writing inverted records into sorted order -> linear branchless composite
// on the first 256 threads. Culling exact: contribution needs q<=11.09<11.3.

constexpr int P_GAUSS = 1024;
constexpr int IMG_H = 256;
constexpr int IMG_W = 256;
constexpr float Q_GATE = 11.2f;   // alpha>=1/255 iff q<=2*ln255=11.0898
constexpr float Q_CULL = 11.3f;

// staged-raw layout (float offsets): covs | depth | colors
constexpr int RAW_COVS  = 0;      // 3072 floats
constexpr int RAW_DEPTH = 3072;   // 1024
constexpr int RAW_COLS  = 4096;   // 3072
constexpr int RAW_TOT   = 7168;   // 28 KB

__global__ __launch_bounds__(512) void gs_fused(
    const float* __restrict__ means,   // P*2
    const float* __restrict__ covs,    // P*3
    const float* __restrict__ depth,   // P
    const float* __restrict__ colors,  // P*3
    float* __restrict__ out)           // 3*H*W chw
{
    __shared__ float rawbuf[RAW_TOT];       // hit-gather fields
    __shared__ float g[P_GAUSS * 8];        // compacted records, orig order
    __shared__ float g2[P_GAUSS * 8];       // sorted inverted records
    __shared__ float sdepth[P_GAUSS + 4];   // survivor depths (+pad)
    __shared__ int   cnt16[16];

    const int tid = threadIdx.x;
    const int wid = tid >> 6;
    const int lane = tid & 63;

    const float tx0 = (float)(blockIdx.x * 16) + 0.5f;
    const float tx1 = tx0 + 15.0f;
    const float ty0 = (float)(blockIdx.y * 16) + 0.5f;
    const float ty1 = ty0 + 15.0f;

    // ---- staging of hit-gather fields (concurrent with cull loads) ----
    {
        float4* rv = reinterpret_cast<float4*>(rawbuf);
        const float4* cv = reinterpret_cast<const float4*>(covs);
        const float4* dv = reinterpret_cast<const float4*>(depth);
        const float4* lv = reinterpret_cast<const float4*>(colors);
        rv[RAW_COVS / 4 + tid] = cv[tid];
        rv[RAW_COLS / 4 + tid] = lv[tid];
        if (tid < 256) {
            rv[RAW_COVS / 4 + 512 + tid] = cv[512 + tid];
            rv[RAW_COLS / 4 + 512 + tid] = lv[512 + tid];
            rv[RAW_DEPTH / 4 + tid]      = dv[tid];
        }
    }

    // ---- cull directly from global; ballot counts ----
    float mx[2], my[2], ca[2], cc[2];
    unsigned long long msk[2];
    bool hit[2];
#pragma unroll
    for (int r = 0; r < 2; ++r) {
        const int p = r * 512 + tid;
        const float2 m2 = reinterpret_cast<const float2*>(means)[p];
        mx[r] = m2.x; my[r] = m2.y;
        ca[r] = covs[3 * p + 0];
        cc[r] = covs[3 * p + 2];
        const float rx = sqrtf(Q_CULL * ca[r]);
        const float ry = sqrtf(Q_CULL * cc[r]);
        hit[r] = (mx[r] + rx >= tx0) && (mx[r] - rx <= tx1) &&
                 (my[r] + ry >= ty0) && (my[r] - ry <= ty1);
        msk[r] = __ballot(hit[r]);
        if (lane == 0) cnt16[r * 8 + wid] = __popcll(msk[r]);
    }
    __syncthreads();   // cnt16 visible; staging ds_writes complete

    int c16[16];
#pragma unroll
    for (int k = 0; k < 16; ++k) c16[k] = cnt16[k];
    int total = 0;
#pragma unroll
    for (int k = 0; k < 16; ++k) total += c16[k];

    // ---- scatter survivors; gather remaining fields (hits only, from LDS) ----
#pragma unroll
    for (int r = 0; r < 2; ++r) {
        if (hit[r]) {
            const int p = r * 512 + tid;
            const float cb  = rawbuf[RAW_COVS + 3 * p + 1];
            const float dp  = rawbuf[RAW_DEPTH + p];
            const float cr  = rawbuf[RAW_COLS + 3 * p + 0];
            const float cg  = rawbuf[RAW_COLS + 3 * p + 1];
            const float cbl = rawbuf[RAW_COLS + 3 * p + 2];
            const int key = r * 8 + wid;
            int base = 0;
            for (int k = 0; k < key; ++k) base += c16[k];
            const int slot = base + __popcll(msk[r] & ((1ull << lane) - 1ull));
            float4* rec = reinterpret_cast<float4*>(g + slot * 8);
            rec[0] = make_float4(mx[r], my[r], ca[r], cb);
            rec[1] = make_float4(cc[r], cr, cg, cbl);
            sdepth[slot] = dp;
        }
    }
    if (tid < 4) sdepth[total + tid] = FLT_MAX;   // pad for float4 rank loop
    __syncthreads();

    // ---- rank-sort; write inverted record at sorted position ----
    const int limit4 = (total + 3) >> 2;
    for (int s = tid; s < total; s += 512) {
        const float d = sdepth[s];
        int rank = 0;
        const float4* sd4 = reinterpret_cast<const float4*>(sdepth);
        for (int jj = 0; jj < limit4; ++jj) {
            const float4 d4 = sd4[jj];
            const int j = 4 * jj;
            rank += (d4.x < d || (d4.x == d && j + 0 < s)) ? 1 : 0;
            rank += (d4.y < d || (d4.y == d && j + 1 < s)) ? 1 : 0;
            rank += (d4.z < d || (d4.z == d && j + 2 < s)) ? 1 : 0;
            rank += (d4.w < d || (d4.w == d && j + 3 < s)) ? 1 : 0;
        }
        const float4 r0 = reinterpret_cast<const float4*>(g + s * 8)[0]; // mx,my,a,b
        const float4 r1 = reinterpret_cast<const float4*>(g + s * 8)[1]; // c,r,g,b
        const float a = r0.z, b = r0.w, c = r1.x;
        const float inv = 1.0f / (a * c - b * b);
        float4* dst = reinterpret_cast<float4*>(g2 + rank * 8);
        dst[0] = make_float4(r0.x, r0.y, c * inv, -b * inv);   // mx,my,ia,ib
        dst[1] = make_float4(a * inv, r1.y, r1.z, r1.w);       // ic,r,g,b
    }
    __syncthreads();

    // ---- linear front-to-back composite (first 256 threads = 16x16 pixels) ----
    if (tid < 256) {
        const float px = tx0 + (float)(tid & 15);
        const float py = ty0 + (float)(tid >> 4);

        float T = 1.0f;
        float acr = 0.0f, acg = 0.0f, acb = 0.0f;

        const float4* gv = reinterpret_cast<const float4*>(g2);
        float4 A0, B0, A1, B1;
        if (total > 0) { A0 = gv[0]; B0 = gv[1]; }
        if (total > 1) { A1 = gv[2]; B1 = gv[3]; }
        for (int p = 0; p < total; ++p) {
            const float4 c0 = A0;   // mx, my, ia, ib
            const float4 c1 = B0;   // ic, r, g, b
            A0 = A1; B0 = B1;
            if (p + 2 < total) { A1 = gv[2 * p + 4]; B1 = gv[2 * p + 5]; }
            const float dx = px - c0.x;
            const float dy = py - c0.y;
            const float q = c0.z * dx * dx + 2.0f * c0.w * (dx * dy) + c1.x * dy * dy;
            float alpha = fminf(0.99f, __expf(-0.5f * q));
            alpha = (q < Q_GATE && alpha >= (1.0f / 255.0f)) ? alpha : 0.0f;
            const float w = alpha * T;
            acr += w * c1.y;
            acg += w * c1.z;
            acb += w * c1.w;
            T *= (1.0f - alpha);
        }

        const int pix = (blockIdx.y * 16 + (tid >> 4)) * IMG_W + (blockIdx.x * 16 + (tid & 15));
        out[0 * IMG_H * IMG_W + pix] = acr;
        out[1 * IMG_H * IMG_W + pix] = acg;
        out[2 * IMG_H * IMG_W + pix] = acb;
    }
}

extern "C" void kernel_launch(void* const* d_in, const int* in_sizes, int n_in,
                              void* d_out, int out_size, void* d_ws, size_t ws_size,
                              hipStream_t stream) {
    const float* means  = (const float*)d_in[0];
    const float* covs   = (const float*)d_in[1];
    const float* depth  = (const float*)d_in[2];
    const float* colors = (const float*)d_in[3];
    float* out = (float*)d_out;

    gs_fused<<<dim3(IMG_W / 16, IMG_H / 16), dim3(512), 0, stream>>>(
        means, covs, depth, colors, out);
}